// Round 9
// baseline (219.508 us; speedup 1.0000x reference)
//
#include <hip/hip_runtime.h>

// Problem constants
#define SEQ  2048
#define NB   32
#define NS   512
#define MI   64   // M_IN
#define PO   64   // P_OUT
#define TB   64   // t-block
#define NTB  32   // SEQ/TB
#define CH   64   // i-chunk
#define NCH  8    // NS/CH
#define LDU  72   // Gb / Sw stride (ushort)
#define LDD  68   // buDiag stride (float): 16B-aligned rows; scatter/scan 2-way (free)
#define SG_LDA 72 // sgemm LDS stride (ushort)

typedef __attribute__((ext_vector_type(8))) __bf16 bf16x8;
typedef __attribute__((ext_vector_type(4))) float  floatx4;

__device__ inline unsigned short f2bf(float f) {
    unsigned u = __builtin_bit_cast(unsigned, f);
    u += 0x7fff + ((u >> 16) & 1);           // RNE
    return (unsigned short)(u >> 16);
}

// ---------------------------------------------------------------------------
// Fused prep (1024 thr): [0,512) u->bf16 | [512,768) BflatT (2 i/blk)
// | [768,800) q (2 p/blk) | [800,868) B/C/D cvt | 868 = himp (impulse
// response; depends only on `a`, so it overlaps prep's memory-bound blocks
// instead of costing a serial dispatch).
// ---------------------------------------------------------------------------
__global__ void __launch_bounds__(1024) prep_all_kernel(
    const float* __restrict__ u, const float* __restrict__ B,
    const float* __restrict__ C, const float* __restrict__ D,
    const float* __restrict__ a,
    unsigned short* __restrict__ ubf, unsigned short* __restrict__ BflatT,
    unsigned short* __restrict__ Bws, unsigned short* __restrict__ Cws,
    unsigned short* __restrict__ Dws, unsigned short* __restrict__ qT,
    float* __restrict__ hbuf) {
    __shared__ __align__(16) char smem[24576];
    const int bx = blockIdx.x, tid = threadIdx.x;
    if (bx < 512) {                        // ---- uconv
        const size_t base = ((size_t)bx * 1024 + tid) * 8;
        float4 f0 = *(const float4*)(u + base);
        float4 f1 = *(const float4*)(u + base + 4);
        unsigned short tmp[8];
        tmp[0] = f2bf(f0.x); tmp[1] = f2bf(f0.y); tmp[2] = f2bf(f0.z); tmp[3] = f2bf(f0.w);
        tmp[4] = f2bf(f1.x); tmp[5] = f2bf(f1.y); tmp[6] = f2bf(f1.z); tmp[7] = f2bf(f1.w);
        *(uint4*)(ubf + base) = *(uint4*)&tmp[0];
    } else if (bx < 768) {                 // ---- BflatT[i][(j,m)] = B[i-j,m]
        const int i = (bx - 512) * 2 + (tid >> 9);
        const int id = tid & 511;
        const int j = id >> 3, q8 = (id & 7) * 8;
        unsigned short tmp[8];
        if (i >= j) {
            const float4 f0 = *(const float4*)(B + (size_t)(i - j) * MI + q8);
            const float4 f1 = *(const float4*)(B + (size_t)(i - j) * MI + q8 + 4);
            tmp[0] = f2bf(f0.x); tmp[1] = f2bf(f0.y); tmp[2] = f2bf(f0.z); tmp[3] = f2bf(f0.w);
            tmp[4] = f2bf(f1.x); tmp[5] = f2bf(f1.y); tmp[6] = f2bf(f1.z); tmp[7] = f2bf(f1.w);
        } else {
#pragma unroll
            for (int z = 0; z < 8; ++z) tmp[z] = 0;
        }
        *(uint4*)(BflatT + (size_t)i * 4096 + j * 64 + q8) = *(uint4*)&tmp[0];
    } else if (bx < 800) {                 // ---- q: qT[p][j], 2 p per block
        float* a_ext = (float*)smem;       // 1024 floats
        const int p = (bx - 768) * 2 + (tid >> 9);
        const int j0 = tid & 511;
        a_ext[tid] = (tid < NS) ? a[tid] : 0.f;
        __syncthreads();
        float acc0 = 0.f;
        const float4* crow = (const float4*)(C + (size_t)p * NS);
        for (int i4 = 0; i4 < NS / 4; ++i4) {
            const float4 cv = crow[i4];
            const int base = 511 - i4 * 4;
            acc0 += cv.x * a_ext[base + j0]     + cv.y * a_ext[base - 1 + j0] +
                    cv.z * a_ext[base - 2 + j0] + cv.w * a_ext[base - 3 + j0];
        }
        qT[(size_t)p * NS + j0] = f2bf(acc0);
    } else if (bx < 868) {                 // ---- B/C/D bf16 cvt (68*1024 = 69632)
        const int idx = (bx - 800) * 1024 + tid;
        const int nB = NS * MI, nC = PO * NS, nD = PO * MI;
        if (idx < nB) Bws[idx] = f2bf(B[idx]);
        else if (idx < nB + nC) Cws[idx - nB] = f2bf(C[idx - nB]);
        else if (idx < nB + nC + nD) Dws[idx - nB - nC] = f2bf(D[idx - nB - nC]);
    } else {
        // ---------------- himp (1024 threads, R1 design) ----------------
        float* a_l     = (float*)smem;                  // 640 floats (zero-pad)
        float* h_ext   = (float*)(smem + 2560);         // 512 zeros + h[0:2048]
        float* part    = (float*)(smem + 12800);        // 16 * 128
        float* rhs_ext = (float*)(smem + 20992);        // 128 zeros + 128
        const int kk = tid & 63, grp = tid >> 6;        // 16 groups of 64

        for (int x = tid; x < 640; x += 1024) a_l[x] = (x < NS) ? a[x] : 0.f;
        for (int x = tid; x < 640; x += 1024) h_ext[x] = 0.f;
        if (tid < 256) rhs_ext[tid] = 0.f;
        __syncthreads();

        float aw[34];
#pragma unroll
        for (int i = 0; i < 34; ++i) aw[i] = a_l[2 * kk + grp * 32 + i];  // max 639, in pad

        // bootstrap h[0:64]: broadcast scan, 1 shfl + 1 FMA per step
        if (tid < 64) {
            if (tid == 0) h_ext[512] = 1.f;
            float acc = (tid >= 1) ? a_l[tid - 1] : 0.f;   // j=0 term: a[t-1]*h[0]
            for (int s = 1; s < 64; ++s) {
                const float hs = -__shfl(acc, s);
                if (tid == s) h_ext[512 + s] = hs;
                const float av = a_l[(tid > s) ? (tid - 1 - s) : 0];
                acc += (tid > s) ? av * hs : 0.f;
            }
        }
        __syncthreads();

        // 16 uniform doubling/chunk stages
        int t0 = 64;
        while (t0 < SEQ) {
            float acc0 = 0.f, acc1 = 0.f;
#pragma unroll
            for (int m = 0; m < 8; ++m) {
                const float4 hv = *(const float4*)&h_ext[512 + t0 - grp * 32 - 4 - 4 * m];
                acc0 += aw[4 * m + 0] * hv.w + aw[4 * m + 1] * hv.z +
                        aw[4 * m + 2] * hv.y + aw[4 * m + 3] * hv.x;
                acc1 += aw[4 * m + 1] * hv.w + aw[4 * m + 2] * hv.z +
                        aw[4 * m + 3] * hv.y + aw[4 * m + 4] * hv.x;
            }
            *(float2*)&part[grp * 128 + 2 * kk] = make_float2(acc0, acc1);
            __syncthreads();
            if (tid < 128) {
                float r = 0.f;
#pragma unroll
                for (int g = 0; g < 16; ++g) r += part[g * 128 + tid];
                rhs_ext[128 + tid] = -r;
            }
            __syncthreads();
            {
                const int g = tid >> 7, out = tid & 127;
                const int k0 = g * 16;
                float s = 0.f;
#pragma unroll
                for (int k4 = 0; k4 < 4; ++k4) {
                    const float4 h4 = *(const float4*)&h_ext[512 + k0 + 4 * k4];
                    const int base = 128 + out - k0 - 4 * k4;
                    s += h4.x * rhs_ext[base]     + h4.y * rhs_ext[base - 1] +
                         h4.z * rhs_ext[base - 2] + h4.w * rhs_ext[base - 3];
                }
                part[g * 128 + out] = s;
            }
            __syncthreads();
            if (tid < 128) {
                float r = 0.f;
#pragma unroll
                for (int g = 0; g < 8; ++g) r += part[g * 128 + tid];
                h_ext[512 + t0 + tid] = r;
            }
            __syncthreads();
            t0 += (t0 == 64) ? 64 : 128;
        }
        for (int i = tid; i < SEQ; i += 1024) hbuf[i] = h_ext[512 + i];
    }
}

// ---------------------------------------------------------------------------
// S-GEMM: S[(b,k), i] = sum_{(j,m)} BflatT[i][(j,m)] * u[b, k*64+63-j, m]
// ---------------------------------------------------------------------------
__global__ void __launch_bounds__(256) sgemm_kernel(const unsigned short* __restrict__ ubf,
                                                    const unsigned short* __restrict__ BflatT,
                                                    float* __restrict__ Sbuf) {
    __shared__ unsigned short A_l[4 * 64 * SG_LDA];   // 36.9 KB
    __shared__ unsigned short U_l[4 * 32 * SG_LDA];   // 18.4 KB
    const int ib = blockIdx.x, b = blockIdx.y;
    const int tid = threadIdx.x, lane = tid & 63, w = tid >> 6;
    const int row16 = lane & 15, quad = lane >> 4;
    const int i0 = ib * 64;
    floatx4 acc[2];
#pragma unroll
    for (int ns = 0; ns < 2; ++ns) acc[ns] = (floatx4){0.f, 0.f, 0.f, 0.f};

    for (int jg = 0; jg < 16; ++jg) {
#pragma unroll
        for (int r = 0; r < 8; ++r) {
            const int id = tid + r * 256;
            const int row = id >> 5;
            const int jj = (id >> 3) & 3, q8 = (id & 7) * 8;
            const int j = jg * 4 + jj;
            *(uint4*)&A_l[(jj * 64 + row) * SG_LDA + q8] =
                *(const uint4*)(BflatT + (size_t)(i0 + row) * 4096 + j * 64 + q8);
        }
#pragma unroll
        for (int r = 0; r < 4; ++r) {
            const int id = tid + r * 256;
            const int n = id >> 5;
            const int jj = (id >> 3) & 3, q8 = (id & 7) * 8;
            const int j = jg * 4 + jj;
            *(uint4*)&U_l[(jj * 32 + n) * SG_LDA + q8] =
                *(const uint4*)(ubf + ((size_t)b * SEQ + n * 64 + 63 - j) * MI + q8);
        }
        __syncthreads();
#pragma unroll
        for (int jj = 0; jj < 4; ++jj) {
#pragma unroll
            for (int mk = 0; mk < 2; ++mk) {
                const bf16x8 av = *(const bf16x8*)
                    &A_l[(jj * 64 + w * 16 + row16) * SG_LDA + mk * 32 + quad * 8];
#pragma unroll
                for (int ns = 0; ns < 2; ++ns) {
                    const bf16x8 bv = *(const bf16x8*)
                        &U_l[(jj * 32 + ns * 16 + row16) * SG_LDA + mk * 32 + quad * 8];
                    acc[ns] = __builtin_amdgcn_mfma_f32_16x16x32_bf16(av, bv, acc[ns], 0, 0, 0);
                }
            }
        }
        __syncthreads();
    }
#pragma unroll
    for (int ns = 0; ns < 2; ++ns) {
        const int n = ns * 16 + row16;
        float* dst = Sbuf + ((size_t)b * NTB + n) * NS + i0 + w * 16 + quad * 4;
        *(floatx4*)dst = acc[ns];
    }
}

// ---------------------------------------------------------------------------
// ytile (MFMA): per (t-block, batch). Diag-major Bu scatter + in-quad
// segmented scan + C*G accumulation.
// R9 schedule restructure (math identical):
//   * merged region: phase B(ch) + phase A(ch+1) execute back-to-back
//     between b2(ch) and b1(ch+1) -> 16 MFMAs clustered per region.
//   * bf/cf(ch+1) prefetched into registers just before b1 -> the
//     barrier's vmcnt drain overlaps the load latency (loads no longer
//     stall phase A at chunk top).
//   * df (epilogue D-fragments) hoisted to prologue.
// Hazards: buDiag write A(ch+1) after b2 (scan(ch) done) ✓, read scan(ch+1)
// after b1 ✓; Gb write scan(ch) after b1, read B(ch) after b2 ✓.
// ---------------------------------------------------------------------------
__global__ void __launch_bounds__(256, 4) ytile_kernel(
    const unsigned short* __restrict__ ubf, const unsigned short* __restrict__ Bws,
    const unsigned short* __restrict__ Cws, const unsigned short* __restrict__ Dws,
    const float* __restrict__ Sbuf, float* __restrict__ fbuf, float* __restrict__ y) {
    __shared__ __align__(16) float buDiag[TB * LDD];         // 17.4 KB
    __shared__ __align__(16) unsigned short Gb[TB * LDU];    // 9.2 KB
    __shared__ float seedL[NS];                              // 2 KB

    const int blk = blockIdx.x, b = blockIdx.y;
    const int t0 = blk * TB;
    const int tid = threadIdx.x;
    const int lane = tid & 63, w = tid >> 6;
    const int row16 = lane & 15, quad = lane >> 4;

    // scan ownership
    const int dd = lane >> 2, seg = lane & 3;
    const int d  = w * 16 + dd;
    const int tsplit = 63 - d, gseg = tsplit >> 4, jsplit = tsplit & 15;
    const int qb = lane & 60;

    // ---- prologue: seeds from Sbuf closed form (2 per thread, 8-way ILP)
    {
        const int mtop = (blk - 1 < 7) ? (blk - 1) : 7;
#pragma unroll
        for (int half = 0; half < 2; ++half) {
            const int s = tid + half * 256;
            const int i = s - 1, q = i >> 6, r = i & 63;
            const int mmax = (mtop < q) ? mtop : q;      // <0 when s==0
            float sd = 0.f;
#pragma unroll
            for (int m = 0; m < 8; ++m) {
                const bool ok = (m <= mmax);
                long off = ((long)b * NTB + (blk - 1 - m)) * NS + (q - m) * 64 + r;
                off = (off < 0) ? 0 : off;               // clamp: keep addr mapped
                const float v = Sbuf[off];
                sd += ok ? v : 0.f;
            }
            seedL[s] = sd;
        }
    }

    // u B-operand frags direct from global (L2/L3 resident)
    bf16x8 ufr0[4], ufr1[4];
#pragma unroll
    for (int nt = 0; nt < 4; ++nt) {
        const size_t ub = ((size_t)b * SEQ + t0 + nt * 16 + row16) * MI;
        ufr0[nt] = *(const bf16x8*)(ubf + ub + quad * 8);
        ufr1[nt] = *(const bf16x8*)(ubf + ub + 32 + quad * 8);
    }

    // D-fragments hoisted (consumed only in epilogue -> fully hidden)
    const bf16x8 df0 = *(const bf16x8*)(Dws + (size_t)(w * 16 + row16) * MI + quad * 8);
    const bf16x8 df1 = *(const bf16x8*)(Dws + (size_t)(w * 16 + row16) * MI + 32 + quad * 8);

    const size_t bRow = (size_t)(w * 16 + row16) * MI;
    const size_t cRow = (size_t)(w * 16 + row16) * NS;

    // chunk-0 fragments
    bf16x8 bf0 = *(const bf16x8*)(Bws + bRow + quad * 8);
    bf16x8 bf1 = *(const bf16x8*)(Bws + bRow + 32 + quad * 8);
    bf16x8 cf0 = *(const bf16x8*)(Cws + cRow + quad * 8);
    bf16x8 cf1 = *(const bf16x8*)(Cws + cRow + 32 + quad * 8);

    float cB = 0.f;                       // chain-B carry (register, same quad)
    floatx4 accY[4];
#pragma unroll
    for (int nt = 0; nt < 4; ++nt) accY[nt] = (floatx4){0.f, 0.f, 0.f, 0.f};

    // phase A helper (writes buDiag for the given B-fragments)
    auto phaseA = [&](const bf16x8 pb0, const bf16x8 pb1) {
#pragma unroll
        for (int nt = 0; nt < 4; ++nt) {
            floatx4 dacc = {0.f, 0.f, 0.f, 0.f};
            dacc = __builtin_amdgcn_mfma_f32_16x16x32_bf16(pb0, ufr0[nt], dacc, 0, 0, 0);
            dacc = __builtin_amdgcn_mfma_f32_16x16x32_bf16(pb1, ufr1[nt], dacc, 0, 0, 0);
            const int t = nt * 16 + row16;
            const int ibase = w * 16 + quad * 4;
#pragma unroll
            for (int r = 0; r < 4; ++r) {
                const int dscat = (ibase + r - t) & 63;
                buDiag[dscat * LDD + t] = dacc[r];
            }
        }
    };

    phaseA(bf0, bf1);                                      // A(0)

    for (int ch = 0; ch < NCH; ++ch) {
        // prefetch next chunk's fragments (complete during b1 wait)
        bf16x8 nbf0 = bf0, nbf1 = bf1, ncf0 = cf0, ncf1 = cf1;
        if (ch + 1 < NCH) {
            const size_t bOff = (size_t)((ch + 1) * CH) * MI + bRow;
            nbf0 = *(const bf16x8*)(Bws + bOff + quad * 8);
            nbf1 = *(const bf16x8*)(Bws + bOff + 32 + quad * 8);
            ncf0 = *(const bf16x8*)(Cws + cRow + (ch + 1) * CH + quad * 8);
            ncf1 = *(const bf16x8*)(Cws + cRow + (ch + 1) * CH + 32 + quad * 8);
        }
        __syncthreads();                                   // b1: buDiag(ch) ready

        // ---- in-quad segmented scan (registers + shfl only)
        {
            const float sA = seedL[ch * CH + d];
            const float* rowp = &buDiag[d * LDD + seg * 16];
            const float4 v0 = *(const float4*)(rowp + 0);
            const float4 v1 = *(const float4*)(rowp + 4);
            const float4 v2 = *(const float4*)(rowp + 8);
            const float4 v3 = *(const float4*)(rowp + 12);
            float pv[16];
            pv[0]  = v0.x;          pv[1]  = pv[0]  + v0.y;
            pv[2]  = pv[1]  + v0.z; pv[3]  = pv[2]  + v0.w;
            pv[4]  = pv[3]  + v1.x; pv[5]  = pv[4]  + v1.y;
            pv[6]  = pv[5]  + v1.z; pv[7]  = pv[6]  + v1.w;
            pv[8]  = pv[7]  + v2.x; pv[9]  = pv[8]  + v2.y;
            pv[10] = pv[9]  + v2.z; pv[11] = pv[10] + v2.w;
            pv[12] = pv[11] + v3.x; pv[13] = pv[12] + v3.y;
            pv[14] = pv[13] + v3.z; pv[15] = pv[14] + v3.w;
            const float total = pv[15];
            const float tq0 = __shfl(total, qb + 0);
            const float tq1 = __shfl(total, qb + 1);
            const float tq2 = __shfl(total, qb + 2);
            const float off = (seg > 0 ? tq0 : 0.f) + (seg > 1 ? tq1 : 0.f) +
                              (seg > 2 ? tq2 : 0.f);
            // pv[jsplit] with runtime jsplit: static-index select chain
            float plocal = pv[0];
#pragma unroll
            for (int j = 1; j < 16; ++j) plocal = (j == jsplit) ? pv[j] : plocal;
            const float Ps = __shfl(off + plocal, qb + gseg);   // prefix at tsplit
            const float exitv = sA + Ps;                        // chain-A exit
            const float baseLo = sA, baseHi = cB - Ps;
#pragma unroll
            for (int j = 0; j < 16; ++j) {
                const int t = seg * 16 + j;
                const float outv = ((t <= tsplit) ? baseLo : baseHi) + off + pv[j];
                Gb[t * LDU + ((d + t) & 63)] = f2bf(outv);
            }
            if (ch == NCH - 1) {
                if (seg == 0) fbuf[(size_t)b * SEQ + t0 + tsplit] = exitv;
            }
            cB = exitv;
        }
        __syncthreads();                                   // b2: Gb(ch) ready

        // ---- merged MFMA region: B(ch) then A(ch+1)
#pragma unroll
        for (int nt = 0; nt < 4; ++nt) {
            const int t = nt * 16 + row16;
            bf16x8 g0 = *(const bf16x8*)&Gb[t * LDU + quad * 8];
            bf16x8 g1 = *(const bf16x8*)&Gb[t * LDU + 32 + quad * 8];
            accY[nt] = __builtin_amdgcn_mfma_f32_16x16x32_bf16(cf0, g0, accY[nt], 0, 0, 0);
            accY[nt] = __builtin_amdgcn_mfma_f32_16x16x32_bf16(cf1, g1, accY[nt], 0, 0, 0);
        }
        if (ch + 1 < NCH) phaseA(nbf0, nbf1);
        bf0 = nbf0; bf1 = nbf1; cf0 = ncf0; cf1 = ncf1;
    }

    // epilogue: += D*u, store y (df preloaded)
#pragma unroll
    for (int nt = 0; nt < 4; ++nt) {
        const int t = nt * 16 + row16;
        accY[nt] = __builtin_amdgcn_mfma_f32_16x16x32_bf16(df0, ufr0[nt], accY[nt], 0, 0, 0);
        accY[nt] = __builtin_amdgcn_mfma_f32_16x16x32_bf16(df1, ufr1[nt], accY[nt], 0, 0, 0);
        const int p0 = w * 16 + quad * 4;
        *(floatx4*)(y + ((size_t)b * SEQ + t0 + t) * PO + p0) = accY[nt];
    }
}

// ---------------------------------------------------------------------------
// s[b][t] = sum_{j=0..t} h[j] f[b][t-j]  (R3: 4 outputs/thread reg-blocked)
// R7: stores s as bf16 (RNE at the same point corr used to convert).
// ---------------------------------------------------------------------------
__global__ void __launch_bounds__(256) sconv_kernel(const float* __restrict__ fbuf,
                                                    const float* __restrict__ hbuf,
                                                    unsigned short* __restrict__ sbuf) {
    __shared__ __align__(16) float f_l[64 + SEQ];    // 64 zeros + f[0:len)
    __shared__ __align__(16) float h_lc[SEQ + 8];    // h + zero tail
    __shared__ __align__(16) float part[16][TB];
    const int blk = blockIdx.x, b = blockIdx.y, tid = threadIdx.x;
    const int t0 = blk * TB;
    const int len = t0 + TB;
    {
        const float4* fs = (const float4*)(fbuf + (size_t)b * SEQ);
        const float4* hs = (const float4*)hbuf;
        float4* f4 = (float4*)f_l;
        float4* h4p = (float4*)h_lc;
        if (tid < 16) f4[tid] = make_float4(0.f, 0.f, 0.f, 0.f);
        for (int i = tid; i < len / 4; i += 256) f4[16 + i] = fs[i];
        const int nh4 = len / 4 + 2;
        for (int i = tid; i < nh4; i += 256)
            h4p[i] = (i < SEQ / 4) ? hs[i] : make_float4(0.f, 0.f, 0.f, 0.f);
    }
    __syncthreads();
    const int o4 = (tid & 15) * 4, grp = tid >> 4;   // quarter-wave: grp uniform
    const int tb4 = t0 + o4;                         // 4 outputs tb4..tb4+3
    float a0 = 0.f, a1 = 0.f, a2 = 0.f, a3 = 0.f;
    for (int j4 = grp * 4; j4 <= tb4 + 3; j4 += 64) {
        const float4 hv = *(const float4*)&h_lc[j4];
        const int A = tb4 - j4;                      // >= 0, mult of 4
        const float4 q0 = *(const float4*)&f_l[60 + A];
        const float4 q1 = *(const float4*)&f_l[64 + A];
        a0 += hv.x * q1.x + hv.y * q0.w + hv.z * q0.z + hv.w * q0.y;
        a1 += hv.x * q1.y + hv.y * q1.x + hv.z * q0.w + hv.w * q0.z;
        a2 += hv.x * q1.z + hv.y * q1.y + hv.z * q1.x + hv.w * q0.w;
        a3 += hv.x * q1.w + hv.y * q1.z + hv.z * q1.y + hv.w * q1.x;
    }
    *(float4*)&part[grp][o4] = make_float4(a0, a1, a2, a3);
    __syncthreads();
    if (tid < TB) {
        float r = 0.f;
#pragma unroll
        for (int g = 0; g < 16; ++g) r += part[g][tid];
        sbuf[(size_t)b * SEQ + t0 + tid] = f2bf(r);
    }
}

// ---------------------------------------------------------------------------
// corr (MFMA): y[b,t,p] -= sum_j qT[p][j] * s[b, t-1-j]
// R9 schedule restructure (math identical): qf(ch+1) prefetched during
// MFMA(ch); staging(ch+1) moved into the same region after MFMA(ch)
// (Sw double-buffer makes WAR safe); y RMW operands preloaded at start.
// ---------------------------------------------------------------------------
__global__ void __launch_bounds__(256) corr_kernel(
    const unsigned short* __restrict__ sbuf, const unsigned short* __restrict__ qT,
    float* __restrict__ y) {
    __shared__ unsigned short s_bf[NS + TB];
    __shared__ unsigned short Sw[2][TB * LDU];
    const int blk = blockIdx.x, b = blockIdx.y, tid = threadIdx.x;
    const int t0 = blk * TB;
    const int lane = tid & 63, w = tid >> 6;
    const int row16 = lane & 15, quad = lane >> 4;

    // preload y RMW operands (consumed only at the end -> hidden)
    floatx4 oldY[4];
#pragma unroll
    for (int nt = 0; nt < 4; ++nt) {
        const int t = nt * 16 + row16;
        const int p0 = w * 16 + quad * 4;
        oldY[nt] = *(const floatx4*)(y + ((size_t)b * SEQ + t0 + t) * PO + p0);
    }

    for (int idx = tid; idx < NS + TB; idx += 256) {
        const int t = t0 - NS + idx;
        s_bf[idx] = (t >= 0) ? sbuf[(size_t)b * SEQ + t] : (unsigned short)0;
    }

    const size_t qRow = (size_t)(w * 16 + row16) * NS;
    bf16x8 qf0 = *(const bf16x8*)(qT + qRow + quad * 8);
    bf16x8 qf1 = *(const bf16x8*)(qT + qRow + 32 + quad * 8);

    floatx4 acc[4];
#pragma unroll
    for (int nt = 0; nt < 4; ++nt) acc[nt] = (floatx4){0.f, 0.f, 0.f, 0.f};
    __syncthreads();                                   // s_bf ready

    // stage chunk 0
    {
        const int r = tid >> 2, c0 = (tid & 3) * 16;
        unsigned short tmp[16];
        const int base = 511 + r - c0;
#pragma unroll
        for (int jj = 0; jj < 16; ++jj) tmp[jj] = s_bf[base - jj];
        *(uint4*)&Sw[0][r * LDU + c0]     = *(uint4*)&tmp[0];
        *(uint4*)&Sw[0][r * LDU + c0 + 8] = *(uint4*)&tmp[8];
    }
    __syncthreads();                                   // Sw[0] ready

    for (int ch = 0; ch < NCH; ++ch) {
        // prefetch next chunk's q-fragments
        bf16x8 nqf0 = qf0, nqf1 = qf1;
        if (ch + 1 < NCH) {
            nqf0 = *(const bf16x8*)(qT + qRow + (ch + 1) * CH + quad * 8);
            nqf1 = *(const bf16x8*)(qT + qRow + (ch + 1) * CH + 32 + quad * 8);
        }
        // MFMA(ch) on Sw[ch&1]
#pragma unroll
        for (int nt = 0; nt < 4; ++nt) {
            const int t = nt * 16 + row16;
            bf16x8 s0 = *(const bf16x8*)&Sw[ch & 1][t * LDU + quad * 8];
            bf16x8 s1 = *(const bf16x8*)&Sw[ch & 1][t * LDU + 32 + quad * 8];
            acc[nt] = __builtin_amdgcn_mfma_f32_16x16x32_bf16(qf0, s0, acc[nt], 0, 0, 0);
            acc[nt] = __builtin_amdgcn_mfma_f32_16x16x32_bf16(qf1, s1, acc[nt], 0, 0, 0);
        }
        // stage chunk ch+1 into the other buffer (WAR safe: Sw[(ch+1)&1]
        // was last read by MFMA(ch-1), completed before the previous bar)
        if (ch + 1 < NCH) {
            const int r = tid >> 2, c0 = (tid & 3) * 16;
            unsigned short tmp[16];
            const int base = 511 + r - (ch + 1) * CH - c0;
#pragma unroll
            for (int jj = 0; jj < 16; ++jj) tmp[jj] = s_bf[base - jj];
            *(uint4*)&Sw[(ch + 1) & 1][r * LDU + c0]     = *(uint4*)&tmp[0];
            *(uint4*)&Sw[(ch + 1) & 1][r * LDU + c0 + 8] = *(uint4*)&tmp[8];
            __syncthreads();                           // Sw[(ch+1)&1] ready
        }
        qf0 = nqf0; qf1 = nqf1;
    }
#pragma unroll
    for (int nt = 0; nt < 4; ++nt) {
        const int t = nt * 16 + row16;
        const int p0 = w * 16 + quad * 4;
        float* yp = y + ((size_t)b * SEQ + t0 + t) * PO + p0;
        floatx4 o = oldY[nt];
        o.x -= acc[nt].x; o.y -= acc[nt].y; o.z -= acc[nt].z; o.w -= acc[nt].w;
        *(floatx4*)yp = o;
    }
}

// ---------------------------------------------------------------------------
extern "C" void kernel_launch(void* const* d_in, const int* in_sizes, int n_in,
                              void* d_out, int out_size, void* d_ws,
                              size_t ws_size, hipStream_t stream) {
    const float* u  = (const float*)d_in[0];
    const float* a  = (const float*)d_in[1];
    const float* B  = (const float*)d_in[2];
    const float* Cm = (const float*)d_in[3];
    const float* Dm = (const float*)d_in[4];
    float* y = (float*)d_out;

    char* ws = (char*)d_ws;
    unsigned short* Bws = (unsigned short*)ws;                  ws += NS * MI * 2;
    unsigned short* Cws = (unsigned short*)ws;                  ws += PO * NS * 2;
    unsigned short* Dws = (unsigned short*)ws;                  ws += PO * MI * 2;
    unsigned short* qTw = (unsigned short*)ws;                  ws += PO * NS * 2;
    unsigned short* ubf = (unsigned short*)ws;                  ws += (size_t)NB * SEQ * MI * 2;
    unsigned short* Bft = (unsigned short*)ws;                  ws += (size_t)NS * 4096 * 2;
    float* Sbuf = (float*)ws;                                   ws += (size_t)NB * NTB * NS * 4;
    float* fbuf = (float*)ws;                                   ws += (size_t)NB * SEQ * 4;
    unsigned short* sbuf = (unsigned short*)ws;                 ws += (size_t)NB * SEQ * 4;
    float* hbuf = (float*)ws;                                   // 2048 floats

    prep_all_kernel<<<dim3(869), dim3(1024), 0, stream>>>(
        u, B, Cm, Dm, a, ubf, Bft, Bws, Cws, Dws, qTw, hbuf);
    sgemm_kernel<<<dim3(8, 32), dim3(256), 0, stream>>>(ubf, Bft, Sbuf);
    ytile_kernel<<<dim3(NTB, NB), dim3(256), 0, stream>>>(
        ubf, Bws, Cws, Dws, Sbuf, fbuf, y);
    sconv_kernel<<<dim3(NTB, NB), dim3(256), 0, stream>>>(fbuf, hbuf, sbuf);
    corr_kernel<<<dim3(NTB, NB), dim3(256), 0, stream>>>(sbuf, qTw, y);
}

// Round 10
// 191.932 us; speedup vs baseline: 1.1437x; 1.1437x over previous
//
#include <hip/hip_runtime.h>

// Problem constants
#define SEQ  2048
#define NB   32
#define NS   512
#define MI   64   // M_IN
#define PO   64   // P_OUT
#define TB   64   // t-block
#define NTB  32   // SEQ/TB
#define CH   64   // i-chunk
#define NCH  8    // NS/CH
#define LDU  72   // Gb / Sw stride (ushort)
#define LDD  68   // buDiag stride (float): 16B-aligned rows; scatter/scan 2-way (free)
#define SG_LDA 72 // sgemm LDS stride (ushort)

typedef __attribute__((ext_vector_type(8))) __bf16 bf16x8;
typedef __attribute__((ext_vector_type(4))) float  floatx4;

__device__ inline unsigned short f2bf(float f) {
    unsigned u = __builtin_bit_cast(unsigned, f);
    u += 0x7fff + ((u >> 16) & 1);           // RNE
    return (unsigned short)(u >> 16);
}

// ---------------------------------------------------------------------------
// Fused prep (1024 thr): [0,512) u->bf16 | [512,768) BflatT (2 i/blk)
// | [768,800) q (2 p/blk) | [800,868) B/C/D cvt | 868 = himp (impulse
// response; depends only on `a`, so it overlaps prep's memory-bound blocks
// instead of costing a serial dispatch).
// ---------------------------------------------------------------------------
__global__ void __launch_bounds__(1024) prep_all_kernel(
    const float* __restrict__ u, const float* __restrict__ B,
    const float* __restrict__ C, const float* __restrict__ D,
    const float* __restrict__ a,
    unsigned short* __restrict__ ubf, unsigned short* __restrict__ BflatT,
    unsigned short* __restrict__ Bws, unsigned short* __restrict__ Cws,
    unsigned short* __restrict__ Dws, unsigned short* __restrict__ qT,
    float* __restrict__ hbuf) {
    __shared__ __align__(16) char smem[24576];
    const int bx = blockIdx.x, tid = threadIdx.x;
    if (bx < 512) {                        // ---- uconv
        const size_t base = ((size_t)bx * 1024 + tid) * 8;
        float4 f0 = *(const float4*)(u + base);
        float4 f1 = *(const float4*)(u + base + 4);
        unsigned short tmp[8];
        tmp[0] = f2bf(f0.x); tmp[1] = f2bf(f0.y); tmp[2] = f2bf(f0.z); tmp[3] = f2bf(f0.w);
        tmp[4] = f2bf(f1.x); tmp[5] = f2bf(f1.y); tmp[6] = f2bf(f1.z); tmp[7] = f2bf(f1.w);
        *(uint4*)(ubf + base) = *(uint4*)&tmp[0];
    } else if (bx < 768) {                 // ---- BflatT[i][(j,m)] = B[i-j,m]
        const int i = (bx - 512) * 2 + (tid >> 9);
        const int id = tid & 511;
        const int j = id >> 3, q8 = (id & 7) * 8;
        unsigned short tmp[8];
        if (i >= j) {
            const float4 f0 = *(const float4*)(B + (size_t)(i - j) * MI + q8);
            const float4 f1 = *(const float4*)(B + (size_t)(i - j) * MI + q8 + 4);
            tmp[0] = f2bf(f0.x); tmp[1] = f2bf(f0.y); tmp[2] = f2bf(f0.z); tmp[3] = f2bf(f0.w);
            tmp[4] = f2bf(f1.x); tmp[5] = f2bf(f1.y); tmp[6] = f2bf(f1.z); tmp[7] = f2bf(f1.w);
        } else {
#pragma unroll
            for (int z = 0; z < 8; ++z) tmp[z] = 0;
        }
        *(uint4*)(BflatT + (size_t)i * 4096 + j * 64 + q8) = *(uint4*)&tmp[0];
    } else if (bx < 800) {                 // ---- q: qT[p][j], 2 p per block
        float* a_ext = (float*)smem;       // 1024 floats
        const int p = (bx - 768) * 2 + (tid >> 9);
        const int j0 = tid & 511;
        a_ext[tid] = (tid < NS) ? a[tid] : 0.f;
        __syncthreads();
        float acc0 = 0.f;
        const float4* crow = (const float4*)(C + (size_t)p * NS);
        for (int i4 = 0; i4 < NS / 4; ++i4) {
            const float4 cv = crow[i4];
            const int base = 511 - i4 * 4;
            acc0 += cv.x * a_ext[base + j0]     + cv.y * a_ext[base - 1 + j0] +
                    cv.z * a_ext[base - 2 + j0] + cv.w * a_ext[base - 3 + j0];
        }
        qT[(size_t)p * NS + j0] = f2bf(acc0);
    } else if (bx < 868) {                 // ---- B/C/D bf16 cvt (68*1024 = 69632)
        const int idx = (bx - 800) * 1024 + tid;
        const int nB = NS * MI, nC = PO * NS, nD = PO * MI;
        if (idx < nB) Bws[idx] = f2bf(B[idx]);
        else if (idx < nB + nC) Cws[idx - nB] = f2bf(C[idx - nB]);
        else if (idx < nB + nC + nD) Dws[idx - nB - nC] = f2bf(D[idx - nB - nC]);
    } else {
        // ---------------- himp (1024 threads, R1 design) ----------------
        float* a_l     = (float*)smem;                  // 640 floats (zero-pad)
        float* h_ext   = (float*)(smem + 2560);         // 512 zeros + h[0:2048]
        float* part    = (float*)(smem + 12800);        // 16 * 128
        float* rhs_ext = (float*)(smem + 20992);        // 128 zeros + 128
        const int kk = tid & 63, grp = tid >> 6;        // 16 groups of 64

        for (int x = tid; x < 640; x += 1024) a_l[x] = (x < NS) ? a[x] : 0.f;
        for (int x = tid; x < 640; x += 1024) h_ext[x] = 0.f;
        if (tid < 256) rhs_ext[tid] = 0.f;
        __syncthreads();

        float aw[34];
#pragma unroll
        for (int i = 0; i < 34; ++i) aw[i] = a_l[2 * kk + grp * 32 + i];  // max 639, in pad

        // bootstrap h[0:64]: broadcast scan, 1 shfl + 1 FMA per step
        if (tid < 64) {
            if (tid == 0) h_ext[512] = 1.f;
            float acc = (tid >= 1) ? a_l[tid - 1] : 0.f;   // j=0 term: a[t-1]*h[0]
            for (int s = 1; s < 64; ++s) {
                const float hs = -__shfl(acc, s);
                if (tid == s) h_ext[512 + s] = hs;
                const float av = a_l[(tid > s) ? (tid - 1 - s) : 0];
                acc += (tid > s) ? av * hs : 0.f;
            }
        }
        __syncthreads();

        // 16 uniform doubling/chunk stages
        int t0 = 64;
        while (t0 < SEQ) {
            float acc0 = 0.f, acc1 = 0.f;
#pragma unroll
            for (int m = 0; m < 8; ++m) {
                const float4 hv = *(const float4*)&h_ext[512 + t0 - grp * 32 - 4 - 4 * m];
                acc0 += aw[4 * m + 0] * hv.w + aw[4 * m + 1] * hv.z +
                        aw[4 * m + 2] * hv.y + aw[4 * m + 3] * hv.x;
                acc1 += aw[4 * m + 1] * hv.w + aw[4 * m + 2] * hv.z +
                        aw[4 * m + 3] * hv.y + aw[4 * m + 4] * hv.x;
            }
            *(float2*)&part[grp * 128 + 2 * kk] = make_float2(acc0, acc1);
            __syncthreads();
            if (tid < 128) {
                float r = 0.f;
#pragma unroll
                for (int g = 0; g < 16; ++g) r += part[g * 128 + tid];
                rhs_ext[128 + tid] = -r;
            }
            __syncthreads();
            {
                const int g = tid >> 7, out = tid & 127;
                const int k0 = g * 16;
                float s = 0.f;
#pragma unroll
                for (int k4 = 0; k4 < 4; ++k4) {
                    const float4 h4 = *(const float4*)&h_ext[512 + k0 + 4 * k4];
                    const int base = 128 + out - k0 - 4 * k4;
                    s += h4.x * rhs_ext[base]     + h4.y * rhs_ext[base - 1] +
                         h4.z * rhs_ext[base - 2] + h4.w * rhs_ext[base - 3];
                }
                part[g * 128 + out] = s;
            }
            __syncthreads();
            if (tid < 128) {
                float r = 0.f;
#pragma unroll
                for (int g = 0; g < 8; ++g) r += part[g * 128 + tid];
                h_ext[512 + t0 + tid] = r;
            }
            __syncthreads();
            t0 += (t0 == 64) ? 64 : 128;
        }
        for (int i = tid; i < SEQ; i += 1024) hbuf[i] = h_ext[512 + i];
    }
}

// ---------------------------------------------------------------------------
// S-GEMM: S[(b,k), i] = sum_{(j,m)} BflatT[i][(j,m)] * u[b, k*64+63-j, m]
// R10: double-buffered staging (110.6 KB LDS; grid is 1 block/CU so no
// occupancy change). stage(jg+1) issues before MFMA(jg); single barrier
// per iteration. MFMA(jg) doesn't depend on stage(jg+1), so the compiler
// can sink the waitcnt+ds_write below the MFMAs -> staging latency hides
// under compute instead of being fully exposed (old: stage->bar->MFMA->bar).
// WAR safe: barrier(jg) ensures MFMA(jg) reads of buf[jg&1] complete before
// stage(jg+2) overwrites it in iteration jg+1.
// ---------------------------------------------------------------------------
__global__ void __launch_bounds__(256) sgemm_kernel(const unsigned short* __restrict__ ubf,
                                                    const unsigned short* __restrict__ BflatT,
                                                    float* __restrict__ Sbuf) {
    __shared__ unsigned short A_l[2][4 * 64 * SG_LDA];   // 73.7 KB
    __shared__ unsigned short U_l[2][4 * 32 * SG_LDA];   // 36.9 KB
    const int ib = blockIdx.x, b = blockIdx.y;
    const int tid = threadIdx.x, lane = tid & 63, w = tid >> 6;
    const int row16 = lane & 15, quad = lane >> 4;
    const int i0 = ib * 64;
    floatx4 acc[2];
#pragma unroll
    for (int ns = 0; ns < 2; ++ns) acc[ns] = (floatx4){0.f, 0.f, 0.f, 0.f};

    auto stage = [&](int jg, int buf) {
#pragma unroll
        for (int r = 0; r < 8; ++r) {
            const int id = tid + r * 256;
            const int row = id >> 5;
            const int jj = (id >> 3) & 3, q8 = (id & 7) * 8;
            const int j = jg * 4 + jj;
            *(uint4*)&A_l[buf][(jj * 64 + row) * SG_LDA + q8] =
                *(const uint4*)(BflatT + (size_t)(i0 + row) * 4096 + j * 64 + q8);
        }
#pragma unroll
        for (int r = 0; r < 4; ++r) {
            const int id = tid + r * 256;
            const int n = id >> 5;
            const int jj = (id >> 3) & 3, q8 = (id & 7) * 8;
            const int j = jg * 4 + jj;
            *(uint4*)&U_l[buf][(jj * 32 + n) * SG_LDA + q8] =
                *(const uint4*)(ubf + ((size_t)b * SEQ + n * 64 + 63 - j) * MI + q8);
        }
    };

    stage(0, 0);
    __syncthreads();
    for (int jg = 0; jg < 16; ++jg) {
        const int cur = jg & 1;
        if (jg + 1 < 16) stage(jg + 1, cur ^ 1);
#pragma unroll
        for (int jj = 0; jj < 4; ++jj) {
#pragma unroll
            for (int mk = 0; mk < 2; ++mk) {
                const bf16x8 av = *(const bf16x8*)
                    &A_l[cur][(jj * 64 + w * 16 + row16) * SG_LDA + mk * 32 + quad * 8];
#pragma unroll
                for (int ns = 0; ns < 2; ++ns) {
                    const bf16x8 bv = *(const bf16x8*)
                        &U_l[cur][(jj * 32 + ns * 16 + row16) * SG_LDA + mk * 32 + quad * 8];
                    acc[ns] = __builtin_amdgcn_mfma_f32_16x16x32_bf16(av, bv, acc[ns], 0, 0, 0);
                }
            }
        }
        __syncthreads();
    }
#pragma unroll
    for (int ns = 0; ns < 2; ++ns) {
        const int n = ns * 16 + row16;
        float* dst = Sbuf + ((size_t)b * NTB + n) * NS + i0 + w * 16 + quad * 4;
        *(floatx4*)dst = acc[ns];
    }
}

// ---------------------------------------------------------------------------
// ytile (MFMA): per (t-block, batch). Diag-major Bu scatter + in-quad
// segmented scan + C*G accumulation. (R8 version — best measured.)
// R9's merged-region + register-prefetch REVERTED: both R6 and R9 show the
// spill signature (WRITE_SIZE +14-18 MB) — holding prefetched fragments
// live across barriers spills at the 64-VGPR allocation.
// ---------------------------------------------------------------------------
__global__ void __launch_bounds__(256, 4) ytile_kernel(
    const unsigned short* __restrict__ ubf, const unsigned short* __restrict__ Bws,
    const unsigned short* __restrict__ Cws, const unsigned short* __restrict__ Dws,
    const float* __restrict__ Sbuf, float* __restrict__ fbuf, float* __restrict__ y) {
    __shared__ __align__(16) float buDiag[TB * LDD];         // 17.4 KB
    __shared__ __align__(16) unsigned short Gb[TB * LDU];    // 9.2 KB
    __shared__ float seedL[NS];                              // 2 KB

    const int blk = blockIdx.x, b = blockIdx.y;
    const int t0 = blk * TB;
    const int tid = threadIdx.x;
    const int lane = tid & 63, w = tid >> 6;
    const int row16 = lane & 15, quad = lane >> 4;

    // scan ownership
    const int dd = lane >> 2, seg = lane & 3;
    const int d  = w * 16 + dd;
    const int tsplit = 63 - d, gseg = tsplit >> 4, jsplit = tsplit & 15;
    const int qb = lane & 60;

    // ---- prologue: seeds from Sbuf closed form (2 per thread, 8-way ILP)
    {
        const int mtop = (blk - 1 < 7) ? (blk - 1) : 7;
#pragma unroll
        for (int half = 0; half < 2; ++half) {
            const int s = tid + half * 256;
            const int i = s - 1, q = i >> 6, r = i & 63;
            const int mmax = (mtop < q) ? mtop : q;      // <0 when s==0
            float sd = 0.f;
#pragma unroll
            for (int m = 0; m < 8; ++m) {
                const bool ok = (m <= mmax);
                long off = ((long)b * NTB + (blk - 1 - m)) * NS + (q - m) * 64 + r;
                off = (off < 0) ? 0 : off;               // clamp: keep addr mapped
                const float v = Sbuf[off];
                sd += ok ? v : 0.f;
            }
            seedL[s] = sd;
        }
    }

    float cB = 0.f;                       // chain-B carry (register, same quad)

    floatx4 accY[4];
#pragma unroll
    for (int nt = 0; nt < 4; ++nt) accY[nt] = (floatx4){0.f, 0.f, 0.f, 0.f};

    // u B-operand frags direct from global (L2/L3 resident)
    bf16x8 ufr0[4], ufr1[4];
#pragma unroll
    for (int nt = 0; nt < 4; ++nt) {
        const size_t ub = ((size_t)b * SEQ + t0 + nt * 16 + row16) * MI;
        ufr0[nt] = *(const bf16x8*)(ubf + ub + quad * 8);
        ufr1[nt] = *(const bf16x8*)(ubf + ub + 32 + quad * 8);
    }

    for (int ch = 0; ch < NCH; ++ch) {
        const bf16x8 bf0 = *(const bf16x8*)(Bws + (size_t)(ch * CH + w * 16 + row16) * MI + quad * 8);
        const bf16x8 bf1 = *(const bf16x8*)(Bws + (size_t)(ch * CH + w * 16 + row16) * MI + 32 + quad * 8);
        const bf16x8 cf0 = *(const bf16x8*)(Cws + (size_t)(w * 16 + row16) * NS + ch * CH + quad * 8);
        const bf16x8 cf1 = *(const bf16x8*)(Cws + (size_t)(w * 16 + row16) * NS + ch * CH + 32 + quad * 8);

        // phase A: Bu chunk -> buDiag (diag-major scatter; 2-way banks = free)
#pragma unroll
        for (int nt = 0; nt < 4; ++nt) {
            floatx4 dacc = {0.f, 0.f, 0.f, 0.f};
            dacc = __builtin_amdgcn_mfma_f32_16x16x32_bf16(bf0, ufr0[nt], dacc, 0, 0, 0);
            dacc = __builtin_amdgcn_mfma_f32_16x16x32_bf16(bf1, ufr1[nt], dacc, 0, 0, 0);
            const int t = nt * 16 + row16;
            const int ibase = w * 16 + quad * 4;
#pragma unroll
            for (int r = 0; r < 4; ++r) {
                const int dscat = (ibase + r - t) & 63;
                buDiag[dscat * LDD + t] = dacc[r];
            }
        }
        __syncthreads();                                   // b1: buDiag+seedL ready

        // ---- in-quad segmented scan (registers + shfl only)
        {
            const float sA = seedL[ch * CH + d];
            const float* rowp = &buDiag[d * LDD + seg * 16];
            const float4 v0 = *(const float4*)(rowp + 0);
            const float4 v1 = *(const float4*)(rowp + 4);
            const float4 v2 = *(const float4*)(rowp + 8);
            const float4 v3 = *(const float4*)(rowp + 12);
            float pv[16];
            pv[0]  = v0.x;          pv[1]  = pv[0]  + v0.y;
            pv[2]  = pv[1]  + v0.z; pv[3]  = pv[2]  + v0.w;
            pv[4]  = pv[3]  + v1.x; pv[5]  = pv[4]  + v1.y;
            pv[6]  = pv[5]  + v1.z; pv[7]  = pv[6]  + v1.w;
            pv[8]  = pv[7]  + v2.x; pv[9]  = pv[8]  + v2.y;
            pv[10] = pv[9]  + v2.z; pv[11] = pv[10] + v2.w;
            pv[12] = pv[11] + v3.x; pv[13] = pv[12] + v3.y;
            pv[14] = pv[13] + v3.z; pv[15] = pv[14] + v3.w;
            const float total = pv[15];
            const float tq0 = __shfl(total, qb + 0);
            const float tq1 = __shfl(total, qb + 1);
            const float tq2 = __shfl(total, qb + 2);
            const float off = (seg > 0 ? tq0 : 0.f) + (seg > 1 ? tq1 : 0.f) +
                              (seg > 2 ? tq2 : 0.f);
            // pv[jsplit] with runtime jsplit: static-index select chain
            float plocal = pv[0];
#pragma unroll
            for (int j = 1; j < 16; ++j) plocal = (j == jsplit) ? pv[j] : plocal;
            const float Ps = __shfl(off + plocal, qb + gseg);   // prefix at tsplit
            const float exitv = sA + Ps;                        // chain-A exit
            const float baseLo = sA, baseHi = cB - Ps;
#pragma unroll
            for (int j = 0; j < 16; ++j) {
                const int t = seg * 16 + j;
                const float outv = ((t <= tsplit) ? baseLo : baseHi) + off + pv[j];
                Gb[t * LDU + ((d + t) & 63)] = f2bf(outv);
            }
            if (ch == NCH - 1) {
                if (seg == 0) fbuf[(size_t)b * SEQ + t0 + tsplit] = exitv;
            }
            cB = exitv;
        }
        __syncthreads();                                   // b2: Gb ready

        // phase B: accY += C[:,chunk] * G[chunk]  (bf16 direct)
#pragma unroll
        for (int nt = 0; nt < 4; ++nt) {
            const int t = nt * 16 + row16;
            bf16x8 g0 = *(const bf16x8*)&Gb[t * LDU + quad * 8];
            bf16x8 g1 = *(const bf16x8*)&Gb[t * LDU + 32 + quad * 8];
            accY[nt] = __builtin_amdgcn_mfma_f32_16x16x32_bf16(cf0, g0, accY[nt], 0, 0, 0);
            accY[nt] = __builtin_amdgcn_mfma_f32_16x16x32_bf16(cf1, g1, accY[nt], 0, 0, 0);
        }
    }

    // epilogue: += D*u, store y
    const bf16x8 df0 = *(const bf16x8*)(Dws + (size_t)(w * 16 + row16) * MI + quad * 8);
    const bf16x8 df1 = *(const bf16x8*)(Dws + (size_t)(w * 16 + row16) * MI + 32 + quad * 8);
#pragma unroll
    for (int nt = 0; nt < 4; ++nt) {
        const int t = nt * 16 + row16;
        accY[nt] = __builtin_amdgcn_mfma_f32_16x16x32_bf16(df0, ufr0[nt], accY[nt], 0, 0, 0);
        accY[nt] = __builtin_amdgcn_mfma_f32_16x16x32_bf16(df1, ufr1[nt], accY[nt], 0, 0, 0);
        const int p0 = w * 16 + quad * 4;
        *(floatx4*)(y + ((size_t)b * SEQ + t0 + t) * PO + p0) = accY[nt];
    }
}

// ---------------------------------------------------------------------------
// s[b][t] = sum_{j=0..t} h[j] f[b][t-j]  (R3: 4 outputs/thread reg-blocked)
// R7: stores s as bf16 (RNE at the same point corr used to convert).
// ---------------------------------------------------------------------------
__global__ void __launch_bounds__(256) sconv_kernel(const float* __restrict__ fbuf,
                                                    const float* __restrict__ hbuf,
                                                    unsigned short* __restrict__ sbuf) {
    __shared__ __align__(16) float f_l[64 + SEQ];    // 64 zeros + f[0:len)
    __shared__ __align__(16) float h_lc[SEQ + 8];    // h + zero tail
    __shared__ __align__(16) float part[16][TB];
    const int blk = blockIdx.x, b = blockIdx.y, tid = threadIdx.x;
    const int t0 = blk * TB;
    const int len = t0 + TB;
    {
        const float4* fs = (const float4*)(fbuf + (size_t)b * SEQ);
        const float4* hs = (const float4*)hbuf;
        float4* f4 = (float4*)f_l;
        float4* h4p = (float4*)h_lc;
        if (tid < 16) f4[tid] = make_float4(0.f, 0.f, 0.f, 0.f);
        for (int i = tid; i < len / 4; i += 256) f4[16 + i] = fs[i];
        const int nh4 = len / 4 + 2;
        for (int i = tid; i < nh4; i += 256)
            h4p[i] = (i < SEQ / 4) ? hs[i] : make_float4(0.f, 0.f, 0.f, 0.f);
    }
    __syncthreads();
    const int o4 = (tid & 15) * 4, grp = tid >> 4;   // quarter-wave: grp uniform
    const int tb4 = t0 + o4;                         // 4 outputs tb4..tb4+3
    float a0 = 0.f, a1 = 0.f, a2 = 0.f, a3 = 0.f;
    for (int j4 = grp * 4; j4 <= tb4 + 3; j4 += 64) {
        const float4 hv = *(const float4*)&h_lc[j4];
        const int A = tb4 - j4;                      // >= 0, mult of 4
        const float4 q0 = *(const float4*)&f_l[60 + A];
        const float4 q1 = *(const float4*)&f_l[64 + A];
        a0 += hv.x * q1.x + hv.y * q0.w + hv.z * q0.z + hv.w * q0.y;
        a1 += hv.x * q1.y + hv.y * q1.x + hv.z * q0.w + hv.w * q0.z;
        a2 += hv.x * q1.z + hv.y * q1.y + hv.z * q1.x + hv.w * q0.w;
        a3 += hv.x * q1.w + hv.y * q1.z + hv.z * q1.y + hv.w * q1.x;
    }
    *(float4*)&part[grp][o4] = make_float4(a0, a1, a2, a3);
    __syncthreads();
    if (tid < TB) {
        float r = 0.f;
#pragma unroll
        for (int g = 0; g < 16; ++g) r += part[g][tid];
        sbuf[(size_t)b * SEQ + t0 + tid] = f2bf(r);
    }
}

// ---------------------------------------------------------------------------
// corr (MFMA, direct global q-frags, double-buffered Sw, 1 barrier/chunk):
// y[b,t,p] -= sum_j qT[p][j] * s[b, t-1-j]
// R7: sbuf is already bf16 (sconv converts) -> staging is pure copies.
// ---------------------------------------------------------------------------
__global__ void __launch_bounds__(256) corr_kernel(
    const unsigned short* __restrict__ sbuf, const unsigned short* __restrict__ qT,
    float* __restrict__ y) {
    __shared__ unsigned short s_bf[NS + TB];
    __shared__ unsigned short Sw[2][TB * LDU];
    const int blk = blockIdx.x, b = blockIdx.y, tid = threadIdx.x;
    const int t0 = blk * TB;
    const int lane = tid & 63, w = tid >> 6;
    const int row16 = lane & 15, quad = lane >> 4;
    for (int idx = tid; idx < NS + TB; idx += 256) {
        const int t = t0 - NS + idx;
        s_bf[idx] = (t >= 0) ? sbuf[(size_t)b * SEQ + t] : (unsigned short)0;
    }
    floatx4 acc[4];
#pragma unroll
    for (int nt = 0; nt < 4; ++nt) acc[nt] = (floatx4){0.f, 0.f, 0.f, 0.f};
    __syncthreads();

    for (int ch = 0; ch < NCH; ++ch) {
        const int buf = ch & 1;
        const bf16x8 qf0 = *(const bf16x8*)(qT + (size_t)(w * 16 + row16) * NS + ch * CH + quad * 8);
        const bf16x8 qf1 = *(const bf16x8*)(qT + (size_t)(w * 16 + row16) * NS + ch * CH + 32 + quad * 8);
        {
            const int r = tid >> 2, c0 = (tid & 3) * 16;
            unsigned short tmp[16];
            const int base = 511 + r - ch * CH - c0;
#pragma unroll
            for (int jj = 0; jj < 16; ++jj) tmp[jj] = s_bf[base - jj];
            *(uint4*)&Sw[buf][r * LDU + c0]     = *(uint4*)&tmp[0];
            *(uint4*)&Sw[buf][r * LDU + c0 + 8] = *(uint4*)&tmp[8];
        }
        __syncthreads();
#pragma unroll
        for (int nt = 0; nt < 4; ++nt) {
            const int t = nt * 16 + row16;
            bf16x8 s0 = *(const bf16x8*)&Sw[buf][t * LDU + quad * 8];
            bf16x8 s1 = *(const bf16x8*)&Sw[buf][t * LDU + 32 + quad * 8];
            acc[nt] = __builtin_amdgcn_mfma_f32_16x16x32_bf16(qf0, s0, acc[nt], 0, 0, 0);
            acc[nt] = __builtin_amdgcn_mfma_f32_16x16x32_bf16(qf1, s1, acc[nt], 0, 0, 0);
        }
    }
#pragma unroll
    for (int nt = 0; nt < 4; ++nt) {
        const int t = nt * 16 + row16;
        const int p0 = w * 16 + quad * 4;
        float* yp = y + ((size_t)b * SEQ + t0 + t) * PO + p0;
        floatx4 old = *(const floatx4*)yp;
        *(floatx4*)yp = old - acc[nt];
    }
}

// ---------------------------------------------------------------------------
extern "C" void kernel_launch(void* const* d_in, const int* in_sizes, int n_in,
                              void* d_out, int out_size, void* d_ws,
                              size_t ws_size, hipStream_t stream) {
    const float* u  = (const float*)d_in[0];
    const float* a  = (const float*)d_in[1];
    const float* B  = (const float*)d_in[2];
    const float* Cm = (const float*)d_in[3];
    const float* Dm = (const float*)d_in[4];
    float* y = (float*)d_out;

    char* ws = (char*)d_ws;
    unsigned short* Bws = (unsigned short*)ws;                  ws += NS * MI * 2;
    unsigned short* Cws = (unsigned short*)ws;                  ws += PO * NS * 2;
    unsigned short* Dws = (unsigned short*)ws;                  ws += PO * MI * 2;
    unsigned short* qTw = (unsigned short*)ws;                  ws += PO * NS * 2;
    unsigned short* ubf = (unsigned short*)ws;                  ws += (size_t)NB * SEQ * MI * 2;
    unsigned short* Bft = (unsigned short*)ws;                  ws += (size_t)NS * 4096 * 2;
    float* Sbuf = (float*)ws;                                   ws += (size_t)NB * NTB * NS * 4;
    float* fbuf = (float*)ws;                                   ws += (size_t)NB * SEQ * 4;
    unsigned short* sbuf = (unsigned short*)ws;                 ws += (size_t)NB * SEQ * 4;
    float* hbuf = (float*)ws;                                   // 2048 floats

    prep_all_kernel<<<dim3(869), dim3(1024), 0, stream>>>(
        u, B, Cm, Dm, a, ubf, Bft, Bws, Cws, Dws, qTw, hbuf);
    sgemm_kernel<<<dim3(8, 32), dim3(256), 0, stream>>>(ubf, Bft, Sbuf);
    ytile_kernel<<<dim3(NTB, NB), dim3(256), 0, stream>>>(
        ubf, Bws, Cws, Dws, Sbuf, fbuf, y);
    sconv_kernel<<<dim3(NTB, NB), dim3(256), 0, stream>>>(fbuf, hbuf, sbuf);
    corr_kernel<<<dim3(NTB, NB), dim3(256), 0, stream>>>(sbuf, qTw, y);
}